// Round 1
// baseline (666.003 us; speedup 1.0000x reference)
//
#include <hip/hip_runtime.h>
#include <hip/hip_bf16.h>
#include <cstdint>
#include <cstddef>

// Problem constants
#define T_TOK 4096
#define D_DIM 1024
#define E_EXP 8
#define KSEL 2
#define CAP 1280      // floor(2*1.25*4096/8) = 1280, already even
#define HID_DIM 4096

typedef __attribute__((ext_vector_type(8))) __bf16 bf16x8;
typedef __attribute__((ext_vector_type(4))) float floatx4;

__device__ __forceinline__ unsigned short f2bf(float f) {
  unsigned int u = __builtin_bit_cast(unsigned int, f);
  u = (u + 0x7FFFu + ((u >> 16) & 1u)) >> 16;  // RNE
  return (unsigned short)u;
}
__device__ __forceinline__ float bf2f(unsigned short h) {
  unsigned int u = ((unsigned int)h) << 16;
  return __builtin_bit_cast(float, u);
}

// ---------------- Router: logits, top-2, softmax probs, loss partials ----------------
__global__ void router_kernel(const float* __restrict__ x, const float* __restrict__ wg,
                              int* __restrict__ top1, int* __restrict__ top2,
                              float* __restrict__ p0, float* __restrict__ p1,
                              float* __restrict__ probsum, float* __restrict__ zsum) {
  __shared__ float lps[E_EXP];
  __shared__ float lz;
  if (threadIdx.x < E_EXP) lps[threadIdx.x] = 0.f;
  if (threadIdx.x == 0) lz = 0.f;
  __syncthreads();
  int wave = threadIdx.x >> 6;
  int lane = threadIdx.x & 63;
  int t = blockIdx.x * 4 + wave;
  const float* xr = x + (size_t)t * D_DIM;
  float acc[E_EXP];
#pragma unroll
  for (int e = 0; e < E_EXP; ++e) acc[e] = 0.f;
  for (int j = 0; j < D_DIM / 64; ++j) {
    int i = lane + 64 * j;
    float xv = xr[i];
    const float4* wr = (const float4*)(wg + (size_t)i * E_EXP);
    float4 w0 = wr[0], w1 = wr[1];
    acc[0] += xv * w0.x; acc[1] += xv * w0.y; acc[2] += xv * w0.z; acc[3] += xv * w0.w;
    acc[4] += xv * w1.x; acc[5] += xv * w1.y; acc[6] += xv * w1.z; acc[7] += xv * w1.w;
  }
#pragma unroll
  for (int e = 0; e < E_EXP; ++e) {
#pragma unroll
    for (int s = 32; s > 0; s >>= 1) acc[e] += __shfl_xor(acc[e], s);
  }
  if (lane == 0) {
    int i1 = 0; float v1 = acc[0];
    for (int e = 1; e < E_EXP; ++e) if (acc[e] > v1) { v1 = acc[e]; i1 = e; }
    int i2 = -1; float v2 = -1e30f;
    for (int e = 0; e < E_EXP; ++e) if (e != i1 && acc[e] > v2) { v2 = acc[e]; i2 = e; }
    top1[t] = i1; top2[t] = i2;
    float dexp = expf(v2 - v1);            // softmax over the two kept logits
    p0[t] = 1.f / (1.f + dexp);
    p1[t] = dexp / (1.f + dexp);
    float pe[E_EXP]; float ssum = 0.f;
    for (int e = 0; e < E_EXP; ++e) { pe[e] = expf(acc[e] - v1); ssum += pe[e]; }
    float lse = logf(ssum) + v1;
    atomicAdd(&lz, lse * lse);
    float inv = 1.f / ssum;
    for (int e = 0; e < E_EXP; ++e) atomicAdd(&lps[e], pe[e] * inv);
  }
  __syncthreads();
  if (threadIdx.x < E_EXP) atomicAdd(&probsum[threadIdx.x], lps[threadIdx.x]);
  if (threadIdx.x == 0) atomicAdd(zsum, lz);
}

// -------- Deterministic k-major capacity scan (1 block, 256 thr x 16 tokens) --------
__global__ void scan_kernel(const int* __restrict__ top1, const int* __restrict__ top2,
                            int* __restrict__ rank0, int* __restrict__ rank1,
                            int* __restrict__ slot_token, int* __restrict__ cntk) {
  __shared__ int sc[256][E_EXP];
  int c = threadIdx.x;
  int e0l[16], e1l[16];
  int c0[E_EXP], c1[E_EXP];
#pragma unroll
  for (int e = 0; e < E_EXP; ++e) { c0[e] = 0; c1[e] = 0; }
#pragma unroll
  for (int j = 0; j < 16; ++j) {
    int t = c * 16 + j;
    int a = top1[t]; int b = top2[t];
    e0l[j] = a; e1l[j] = b;
    c0[a]++; c1[b]++;
  }
  // inclusive scan of per-chunk counts (k=0 stream)
  for (int e = 0; e < E_EXP; ++e) sc[c][e] = c0[e];
  __syncthreads();
  for (int s = 1; s < 256; s <<= 1) {
    int tmp[E_EXP];
    if (c >= s) { for (int e = 0; e < E_EXP; ++e) tmp[e] = sc[c - s][e]; }
    __syncthreads();
    if (c >= s) { for (int e = 0; e < E_EXP; ++e) sc[c][e] += tmp[e]; }
    __syncthreads();
  }
  int off0[E_EXP], tot0[E_EXP];
  for (int e = 0; e < E_EXP; ++e) {
    off0[e] = (c > 0) ? sc[c - 1][e] : 0;
    tot0[e] = sc[255][e];
  }
  __syncthreads();
  // k=1 stream
  for (int e = 0; e < E_EXP; ++e) sc[c][e] = c1[e];
  __syncthreads();
  for (int s = 1; s < 256; s <<= 1) {
    int tmp[E_EXP];
    if (c >= s) { for (int e = 0; e < E_EXP; ++e) tmp[e] = sc[c - s][e]; }
    __syncthreads();
    if (c >= s) { for (int e = 0; e < E_EXP; ++e) sc[c][e] += tmp[e]; }
    __syncthreads();
  }
  int off1[E_EXP], tot1[E_EXP];
  for (int e = 0; e < E_EXP; ++e) {
    off1[e] = (c > 0) ? sc[c - 1][e] : 0;
    tot1[e] = sc[255][e];
  }
  // rewalk: assign ranks in exact k-major token order
  int run[E_EXP];
  for (int e = 0; e < E_EXP; ++e) run[e] = off0[e];
#pragma unroll
  for (int j = 0; j < 16; ++j) {
    int t = c * 16 + j;
    int e = e0l[j];
    int r = run[e]++;
    if (r < CAP) { rank0[t] = r; slot_token[e * CAP + r] = t; } else rank0[t] = -1;
  }
  for (int e = 0; e < E_EXP; ++e) run[e] = tot0[e] + off1[e];
#pragma unroll
  for (int j = 0; j < 16; ++j) {
    int t = c * 16 + j;
    int e = e1l[j];
    int r = run[e]++;
    if (r < CAP) { rank1[t] = r; slot_token[e * CAP + r] = t; } else rank1[t] = -1;
  }
  if (c == 0) {
    for (int e = 0; e < E_EXP; ++e) {
      int tot = tot0[e] + tot1[e];
      cntk[e] = tot < CAP ? tot : CAP;
    }
  }
}

// ---------------- Dispatch: gather tokens into expert batches (bf16) ----------------
__global__ void dispatch_kernel(const float* __restrict__ x, const int* __restrict__ slot_token,
                                unsigned short* __restrict__ batch) {
  int slot = blockIdx.x;  // e*CAP + c
  int t = slot_token[slot];
  int d = threadIdx.x * 4;
  ushort4 o;
  if (t >= 0) {
    float4 v = *(const float4*)(x + (size_t)t * D_DIM + d);
    o.x = f2bf(v.x); o.y = f2bf(v.y); o.z = f2bf(v.z); o.w = f2bf(v.w);
  } else {
    o.x = 0; o.y = 0; o.z = 0; o.w = 0;
  }
  *(ushort4*)(batch + (size_t)slot * D_DIM + d) = o;
}

// ------------- Weight transpose + fp32->bf16 convert: in[b][R][C] -> out[b][C][R] -------------
__global__ void transpose_convert(const float* __restrict__ in, unsigned short* __restrict__ out,
                                  int R, int C) {
  __shared__ float tile[32][33];
  int b = blockIdx.z;
  int c0 = blockIdx.x * 32;
  int r0 = blockIdx.y * 32;
  int tx = threadIdx.x;  // 0..31
  int ty = threadIdx.y;  // 0..7
  const float* ip = in + (size_t)b * R * C;
  unsigned short* op = out + (size_t)b * R * C;
#pragma unroll
  for (int j = 0; j < 4; ++j)
    tile[ty + 8 * j][tx] = ip[(size_t)(r0 + ty + 8 * j) * C + (c0 + tx)];
  __syncthreads();
#pragma unroll
  for (int j = 0; j < 4; ++j)
    op[(size_t)(c0 + ty + 8 * j) * R + (r0 + tx)] = f2bf(tile[tx][ty + 8 * j]);
}

// ---------------- bf16 MFMA GEMM: C[M][N] = A[M][KD] * BT[N][KD]^T ----------------
// 128x128 block tile, BK=32, 4 waves each computing 64x64 via 4x4 of 16x16x32 MFMA.
// LDS rows padded 32->40 elems (16B-aligned, kills b128 bank conflicts).
template <int KD, int NN, bool GELU>
__global__ __launch_bounds__(256) void gemm_bt(const unsigned short* __restrict__ A,
                                               const unsigned short* __restrict__ BT,
                                               unsigned short* __restrict__ Cd,
                                               const int* __restrict__ cntk) {
  int e = blockIdx.z;
  int m0 = blockIdx.x * 128;
  int n0 = blockIdx.y * 128;
  if (m0 >= cntk[e]) return;  // skip tiles past this expert's kept-token count
  const unsigned short* Ae = A + (size_t)e * CAP * KD;
  const unsigned short* Be = BT + (size_t)e * NN * KD;
  unsigned short* Ce = Cd + (size_t)e * CAP * NN;
  __shared__ unsigned short As[128 * 40];
  __shared__ unsigned short Bs[128 * 40];
  int tid = threadIdx.x;
  int lane = tid & 63;
  int wv = tid >> 6;
  int wm = (wv & 1) * 64;
  int wn = (wv >> 1) * 64;
  int mrow = lane & 15;
  int kq = (lane >> 4) * 8;
  floatx4 acc[4][4];
#pragma unroll
  for (int i = 0; i < 4; ++i)
#pragma unroll
    for (int j = 0; j < 4; ++j) {
      floatx4 z = {0.f, 0.f, 0.f, 0.f};
      acc[i][j] = z;
    }
  for (int k0 = 0; k0 < KD; k0 += 32) {
    // stage 128x32 A and BT tiles: 512 chunks of 16B each, 2 per thread
#pragma unroll
    for (int i = 0; i < 2; ++i) {
      int ch = i * 256 + tid;
      int r = ch >> 2;
      int cc = (ch & 3) * 8;
      *(bf16x8*)(&As[r * 40 + cc]) = *(const bf16x8*)(&Ae[(size_t)(m0 + r) * KD + k0 + cc]);
      *(bf16x8*)(&Bs[r * 40 + cc]) = *(const bf16x8*)(&Be[(size_t)(n0 + r) * KD + k0 + cc]);
    }
    __syncthreads();
    bf16x8 af[4], bfr[4];
#pragma unroll
    for (int mt = 0; mt < 4; ++mt)
      af[mt] = *(const bf16x8*)(&As[(wm + mt * 16 + mrow) * 40 + kq]);
#pragma unroll
    for (int nt = 0; nt < 4; ++nt)
      bfr[nt] = *(const bf16x8*)(&Bs[(wn + nt * 16 + mrow) * 40 + kq]);
#pragma unroll
    for (int mt = 0; mt < 4; ++mt)
#pragma unroll
      for (int nt = 0; nt < 4; ++nt)
        acc[mt][nt] = __builtin_amdgcn_mfma_f32_16x16x32_bf16(af[mt], bfr[nt], acc[mt][nt], 0, 0, 0);
    __syncthreads();
  }
  // epilogue: C/D layout col=lane&15, row=(lane>>4)*4+reg
  int crow = (lane >> 4) * 4;
  int ccol = lane & 15;
#pragma unroll
  for (int mt = 0; mt < 4; ++mt)
#pragma unroll
    for (int nt = 0; nt < 4; ++nt)
#pragma unroll
      for (int r = 0; r < 4; ++r) {
        float v = acc[mt][nt][r];
        if (GELU) v = 0.5f * v * (1.f + erff(v * 0.70710678118654752f));
        Ce[(size_t)(m0 + wm + mt * 16 + crow + r) * NN + (n0 + wn + nt * 16 + ccol)] = f2bf(v);
      }
}

// ---------------- Combine: out[t] = sum_k w_k * EO[e_k][rank_k] ----------------
__global__ void combine_kernel(const unsigned short* __restrict__ EO,
                               const int* __restrict__ top1, const int* __restrict__ top2,
                               const float* __restrict__ p0, const float* __restrict__ p1,
                               const int* __restrict__ rank0, const int* __restrict__ rank1,
                               float* __restrict__ out) {
  int t = blockIdx.x;
  int d = threadIdx.x * 4;
  float a0 = 0.f, a1 = 0.f, a2 = 0.f, a3 = 0.f;
  int r0 = rank0[t];
  if (r0 >= 0) {
    float w = p0[t];
    ushort4 v = *(const ushort4*)(EO + ((size_t)top1[t] * CAP + r0) * D_DIM + d);
    a0 += w * bf2f(v.x); a1 += w * bf2f(v.y); a2 += w * bf2f(v.z); a3 += w * bf2f(v.w);
  }
  int r1 = rank1[t];
  if (r1 >= 0) {
    float w = p1[t];
    ushort4 v = *(const ushort4*)(EO + ((size_t)top2[t] * CAP + r1) * D_DIM + d);
    a0 += w * bf2f(v.x); a1 += w * bf2f(v.y); a2 += w * bf2f(v.z); a3 += w * bf2f(v.w);
  }
  float4 o; o.x = a0; o.y = a1; o.z = a2; o.w = a3;
  *(float4*)(out + (size_t)t * D_DIM + d) = o;
}

// ---------------- Losses ----------------
__global__ void finalize_kernel(const float* __restrict__ probsum, const float* __restrict__ zsum,
                                const int* __restrict__ cntk, float* __restrict__ out) {
  if (threadIdx.x == 0) {
    float lb = 0.f;
    for (int e = 0; e < E_EXP; ++e)
      lb += (probsum[e] / (float)T_TOK) * ((float)cntk[e] / (float)(T_TOK * KSEL));
    out[(size_t)T_TOK * D_DIM] = lb * (float)E_EXP;
    out[(size_t)T_TOK * D_DIM + 1] = zsum[0] / (float)T_TOK;
  }
}

extern "C" void kernel_launch(void* const* d_in, const int* in_sizes, int n_in,
                              void* d_out, int out_size, void* d_ws, size_t ws_size,
                              hipStream_t stream) {
  const float* x = (const float*)d_in[0];
  const float* w_gate = (const float*)d_in[1];
  const float* w_fc = (const float*)d_in[2];
  const float* w_proj = (const float*)d_in[3];
  float* out = (float*)d_out;
  char* ws = (char*)d_ws;

  // workspace layout (bytes)
  float* probsum = (float*)(ws + 0);            // 8 floats
  float* zsum    = (float*)(ws + 32);           // 1 float
  int*   cntk    = (int*)(ws + 64);             // 8 ints
  int*   top1    = (int*)(ws + 4096);
  int*   top2    = (int*)(ws + 20480);
  float* p0      = (float*)(ws + 36864);
  float* p1      = (float*)(ws + 53248);
  int*   rank0   = (int*)(ws + 69632);
  int*   rank1   = (int*)(ws + 86016);
  int*   slot    = (int*)(ws + 102400);         // E*CAP ints (40960 B)
  unsigned short* batch = (unsigned short*)(ws + 262144);                        // 20.97 MB
  unsigned short* H     = (unsigned short*)(ws + 262144 + 20971520);             // 83.9 MB
  unsigned short* EO    = (unsigned short*)(ws + 262144 + 20971520 + 83886080);  // 20.97 MB
  unsigned short* W     = (unsigned short*)(ws + 262144 + 20971520 + 83886080 + 20971520); // 67.1 MB shared

  hipMemsetAsync(ws, 0, 4096, stream);                              // probsum/zsum
  hipMemsetAsync(slot, 0xFF, E_EXP * CAP * sizeof(int), stream);    // slot_token = -1

  router_kernel<<<T_TOK / 4, 256, 0, stream>>>(x, w_gate, top1, top2, p0, p1, probsum, zsum);
  scan_kernel<<<1, 256, 0, stream>>>(top1, top2, rank0, rank1, slot, cntk);
  dispatch_kernel<<<E_EXP * CAP, 256, 0, stream>>>(x, slot, batch);

  // wT_fc[e][hid][d] <- w_fc[e][d][hid]
  transpose_convert<<<dim3(HID_DIM / 32, D_DIM / 32, E_EXP), dim3(32, 8), 0, stream>>>(w_fc, W, D_DIM, HID_DIM);
  gemm_bt<D_DIM, HID_DIM, true><<<dim3(CAP / 128, HID_DIM / 128, E_EXP), 256, 0, stream>>>(batch, W, H, cntk);

  // wT_proj[e][d][hid] <- w_proj[e][hid][d]  (reuses W after gemm1 completes, stream-ordered)
  transpose_convert<<<dim3(D_DIM / 32, HID_DIM / 32, E_EXP), dim3(32, 8), 0, stream>>>(w_proj, W, HID_DIM, D_DIM);
  gemm_bt<HID_DIM, D_DIM, false><<<dim3(CAP / 128, D_DIM / 128, E_EXP), 256, 0, stream>>>(H, W, EO, cntk);

  combine_kernel<<<T_TOK, 256, 0, stream>>>(EO, top1, top2, p0, p1, rank0, rank1, out);
  finalize_kernel<<<1, 64, 0, stream>>>(probsum, zsum, cntk, out);
}

// Round 2
// 584.106 us; speedup vs baseline: 1.1402x; 1.1402x over previous
//
#include <hip/hip_runtime.h>
#include <hip/hip_bf16.h>
#include <cstdint>
#include <cstddef>

// Problem constants
#define T_TOK 4096
#define D_DIM 1024
#define E_EXP 8
#define KSEL 2
#define CAP 1280      // floor(2*1.25*4096/8) = 1280
#define HID_DIM 4096

typedef __attribute__((ext_vector_type(8))) __bf16 bf16x8;
typedef __attribute__((ext_vector_type(8))) unsigned short ushort8;
typedef __attribute__((ext_vector_type(4))) float floatx4;

__device__ __forceinline__ unsigned short f2bf(float f) {
  unsigned int u = __builtin_bit_cast(unsigned int, f);
  u = (u + 0x7FFFu + ((u >> 16) & 1u)) >> 16;  // RNE
  return (unsigned short)u;
}
__device__ __forceinline__ float bf2f(unsigned short h) {
  unsigned int u = ((unsigned int)h) << 16;
  return __builtin_bit_cast(float, u);
}

// async global->LDS, 16B per lane; lds dest = wave-uniform base + lane*16
__device__ __forceinline__ void async16(const unsigned short* g, unsigned short* l) {
  __builtin_amdgcn_global_load_lds(
      (const __attribute__((address_space(1))) unsigned int*)g,
      (__attribute__((address_space(3))) unsigned int*)l, 16, 0, 0);
}

// ---------------- Router: logits, top-2, softmax probs, loss partials ----------------
__global__ void router_kernel(const float* __restrict__ x, const float* __restrict__ wg,
                              int* __restrict__ top1, int* __restrict__ top2,
                              float* __restrict__ p0, float* __restrict__ p1,
                              float* __restrict__ probsum, float* __restrict__ zsum) {
  __shared__ float lps[E_EXP];
  __shared__ float lz;
  if (threadIdx.x < E_EXP) lps[threadIdx.x] = 0.f;
  if (threadIdx.x == 0) lz = 0.f;
  __syncthreads();
  int wave = threadIdx.x >> 6;
  int lane = threadIdx.x & 63;
  int t = blockIdx.x * 4 + wave;
  const float* xr = x + (size_t)t * D_DIM;
  float acc[E_EXP];
#pragma unroll
  for (int e = 0; e < E_EXP; ++e) acc[e] = 0.f;
  for (int j = 0; j < D_DIM / 64; ++j) {
    int i = lane + 64 * j;
    float xv = xr[i];
    const float4* wr = (const float4*)(wg + (size_t)i * E_EXP);
    float4 w0 = wr[0], w1 = wr[1];
    acc[0] += xv * w0.x; acc[1] += xv * w0.y; acc[2] += xv * w0.z; acc[3] += xv * w0.w;
    acc[4] += xv * w1.x; acc[5] += xv * w1.y; acc[6] += xv * w1.z; acc[7] += xv * w1.w;
  }
#pragma unroll
  for (int e = 0; e < E_EXP; ++e) {
#pragma unroll
    for (int s = 32; s > 0; s >>= 1) acc[e] += __shfl_xor(acc[e], s);
  }
  if (lane == 0) {
    int i1 = 0; float v1 = acc[0];
    for (int e = 1; e < E_EXP; ++e) if (acc[e] > v1) { v1 = acc[e]; i1 = e; }
    int i2 = -1; float v2 = -1e30f;
    for (int e = 0; e < E_EXP; ++e) if (e != i1 && acc[e] > v2) { v2 = acc[e]; i2 = e; }
    top1[t] = i1; top2[t] = i2;
    float dexp = expf(v2 - v1);            // softmax over the two kept logits
    p0[t] = 1.f / (1.f + dexp);
    p1[t] = dexp / (1.f + dexp);
    float pe[E_EXP]; float ssum = 0.f;
    for (int e = 0; e < E_EXP; ++e) { pe[e] = expf(acc[e] - v1); ssum += pe[e]; }
    float lse = logf(ssum) + v1;
    atomicAdd(&lz, lse * lse);
    float inv = 1.f / ssum;
    for (int e = 0; e < E_EXP; ++e) atomicAdd(&lps[e], pe[e] * inv);
  }
  __syncthreads();
  if (threadIdx.x < E_EXP) atomicAdd(&probsum[threadIdx.x], lps[threadIdx.x]);
  if (threadIdx.x == 0) atomicAdd(zsum, lz);
}

// -------- Deterministic k-major capacity scan (1 block, 256 thr x 16 tokens) --------
__global__ void scan_kernel(const int* __restrict__ top1, const int* __restrict__ top2,
                            int* __restrict__ rank0, int* __restrict__ rank1,
                            int* __restrict__ slot_token, int* __restrict__ cntk) {
  __shared__ int sc[256][E_EXP];
  int c = threadIdx.x;
  int e0l[16], e1l[16];
  int c0[E_EXP], c1[E_EXP];
#pragma unroll
  for (int e = 0; e < E_EXP; ++e) { c0[e] = 0; c1[e] = 0; }
#pragma unroll
  for (int j = 0; j < 16; ++j) {
    int t = c * 16 + j;
    int a = top1[t]; int b = top2[t];
    e0l[j] = a; e1l[j] = b;
    c0[a]++; c1[b]++;
  }
  for (int e = 0; e < E_EXP; ++e) sc[c][e] = c0[e];
  __syncthreads();
  for (int s = 1; s < 256; s <<= 1) {
    int tmp[E_EXP];
    if (c >= s) { for (int e = 0; e < E_EXP; ++e) tmp[e] = sc[c - s][e]; }
    __syncthreads();
    if (c >= s) { for (int e = 0; e < E_EXP; ++e) sc[c][e] += tmp[e]; }
    __syncthreads();
  }
  int off0[E_EXP], tot0[E_EXP];
  for (int e = 0; e < E_EXP; ++e) {
    off0[e] = (c > 0) ? sc[c - 1][e] : 0;
    tot0[e] = sc[255][e];
  }
  __syncthreads();
  for (int e = 0; e < E_EXP; ++e) sc[c][e] = c1[e];
  __syncthreads();
  for (int s = 1; s < 256; s <<= 1) {
    int tmp[E_EXP];
    if (c >= s) { for (int e = 0; e < E_EXP; ++e) tmp[e] = sc[c - s][e]; }
    __syncthreads();
    if (c >= s) { for (int e = 0; e < E_EXP; ++e) sc[c][e] += tmp[e]; }
    __syncthreads();
  }
  int off1[E_EXP], tot1[E_EXP];
  for (int e = 0; e < E_EXP; ++e) {
    off1[e] = (c > 0) ? sc[c - 1][e] : 0;
    tot1[e] = sc[255][e];
  }
  int run[E_EXP];
  for (int e = 0; e < E_EXP; ++e) run[e] = off0[e];
#pragma unroll
  for (int j = 0; j < 16; ++j) {
    int t = c * 16 + j;
    int e = e0l[j];
    int r = run[e]++;
    if (r < CAP) { rank0[t] = r; slot_token[e * CAP + r] = t; } else rank0[t] = -1;
  }
  for (int e = 0; e < E_EXP; ++e) run[e] = tot0[e] + off1[e];
#pragma unroll
  for (int j = 0; j < 16; ++j) {
    int t = c * 16 + j;
    int e = e1l[j];
    int r = run[e]++;
    if (r < CAP) { rank1[t] = r; slot_token[e * CAP + r] = t; } else rank1[t] = -1;
  }
  if (c == 0) {
    for (int e = 0; e < E_EXP; ++e) {
      int tot = tot0[e] + tot1[e];
      cntk[e] = tot < CAP ? tot : CAP;
    }
  }
}

// ---------------- Dispatch: gather tokens into expert batches (bf16) ----------------
__global__ void dispatch_kernel(const float* __restrict__ x, const int* __restrict__ slot_token,
                                unsigned short* __restrict__ batch) {
  int slot = blockIdx.x;  // e*CAP + c
  int t = slot_token[slot];
  int d = threadIdx.x * 4;
  ushort4 o;
  if (t >= 0) {
    float4 v = *(const float4*)(x + (size_t)t * D_DIM + d);
    o.x = f2bf(v.x); o.y = f2bf(v.y); o.z = f2bf(v.z); o.w = f2bf(v.w);
  } else {
    o.x = 0; o.y = 0; o.z = 0; o.w = 0;
  }
  *(ushort4*)(batch + (size_t)slot * D_DIM + d) = o;
}

// ------------- Weight transpose + fp32->bf16: in[b][R][C] -> out[b][C][R], 64x64 tiles -------------
__global__ __launch_bounds__(256) void transpose_convert(const float* __restrict__ in,
                                                         unsigned short* __restrict__ out,
                                                         int R, int C) {
  __shared__ float tile[64][65];   // 65-stride: phase-2 col reads land 2-way max (free)
  int b = blockIdx.z;
  int c0 = blockIdx.x * 64;
  int r0 = blockIdx.y * 64;
  const float* ip = in + (size_t)b * R * C;
  unsigned short* op = out + (size_t)b * R * C;
  int tid = threadIdx.x;
  int rr = tid >> 4;          // 0..15
  int cc = (tid & 15) * 4;    // 0..60
#pragma unroll
  for (int it = 0; it < 4; ++it) {
    int r = rr + it * 16;
    float4 v = *(const float4*)(ip + (size_t)(r0 + r) * C + c0 + cc);
    tile[r][cc] = v.x; tile[r][cc + 1] = v.y; tile[r][cc + 2] = v.z; tile[r][cc + 3] = v.w;
  }
  __syncthreads();
  int c = tid >> 2;           // 0..63 (output row within tile)
  int rq = (tid & 3) * 16;    // 0,16,32,48
  unsigned short vals[16];
#pragma unroll
  for (int j = 0; j < 16; ++j) vals[j] = f2bf(tile[rq + j][c]);
  unsigned short* dst = op + (size_t)(c0 + c) * R + r0 + rq;
  *(ushort8*)dst = *(ushort8*)&vals[0];
  *(ushort8*)(dst + 8) = *(ushort8*)&vals[8];
}

// ---------------- bf16 MFMA GEMM, m97-style global_load_lds staging ----------------
// C[M][N] = A[M][KD] * BT[N][KD]^T, 128x128 tile, BK=32, 4 waves x (4x4 16x16x32 MFMA).
// LDS unpadded 128x32 with k-block XOR swizzle: LDS[r][cb] holds global block cb^((r>>1)&3),
// so ds_read_b128 fragment reads hit each 4-bank group exactly 2x (conflict-free per m136).
// Grid is 1D; bid%8 = expert = XCD (8 experts <-> 8 XCDs): each XCD's L2 holds its expert's
// A (2.6 MB) + current B n-group slice, killing the round-1 7x B refetch.
template <int KD, int NN, int NG_TILES, bool GELU>
__global__ __launch_bounds__(256) void gemm_alds(const unsigned short* __restrict__ A,
                                                 const unsigned short* __restrict__ BT,
                                                 unsigned short* __restrict__ Cd,
                                                 const int* __restrict__ cntk) {
  constexpr int MT = CAP / 128;            // 10 m-tiles
  constexpr int GRP = MT * NG_TILES;       // blocks per (expert, n-group)
  int bid = blockIdx.x;
  int e = bid & 7;                          // XCD-pinned expert
  int slot = bid >> 3;
  int ng = slot / GRP;
  int rem = slot - ng * GRP;
  int mm = rem / NG_TILES;
  int nw = rem - mm * NG_TILES;
  int m0 = mm * 128;
  int n0 = (ng * NG_TILES + nw) * 128;
  if (m0 >= cntk[e]) return;               // skip tiles past kept-token count
  const unsigned short* Ae = A + (size_t)e * CAP * KD;
  const unsigned short* Be = BT + (size_t)e * NN * KD;
  unsigned short* Ce = Cd + (size_t)e * CAP * NN;
  __shared__ unsigned short As[128 * 32];
  __shared__ unsigned short Bs[128 * 32];
  int tid = threadIdx.x;
  int lane = tid & 63;
  int wv = tid >> 6;
  int wm = (wv & 1) * 64;
  int wn = (wv >> 1) * 64;
  int mrow = lane & 15;
  int kqb = lane >> 4;                      // 16B-block index of the k-fragment
  int sx = (mrow >> 1) & 3;                 // row swizzle key (16-aligned row bases)
  int kb = (kqb ^ sx) * 8;                  // element offset of swizzled block
  floatx4 acc[4][4];
#pragma unroll
  for (int i = 0; i < 4; ++i)
#pragma unroll
    for (int j = 0; j < 4; ++j) {
      floatx4 z = {0.f, 0.f, 0.f, 0.f};
      acc[i][j] = z;
    }
  for (int k0 = 0; k0 < KD; k0 += 32) {
    // stage 128x32 A and B tiles: 512 16B-chunks each, 2 per thread, direct to LDS
#pragma unroll
    for (int i = 0; i < 2; ++i) {
      int chw = i * 256 + wv * 64;          // wave-uniform chunk base
      int ch = chw + lane;
      int r = ch >> 2;                      // tile row
      int cbs = (ch & 3) ^ ((r >> 1) & 3);  // swizzled global 16B-block
      async16(&Ae[(size_t)(m0 + r) * KD + k0 + cbs * 8], &As[chw * 8]);
      async16(&Be[(size_t)(n0 + r) * KD + k0 + cbs * 8], &Bs[chw * 8]);
    }
    __syncthreads();
    bf16x8 af[4], bfr[4];
#pragma unroll
    for (int mt = 0; mt < 4; ++mt)
      af[mt] = *(const bf16x8*)(&As[(wm + mt * 16 + mrow) * 32 + kb]);
#pragma unroll
    for (int nt = 0; nt < 4; ++nt)
      bfr[nt] = *(const bf16x8*)(&Bs[(wn + nt * 16 + mrow) * 32 + kb]);
#pragma unroll
    for (int mt = 0; mt < 4; ++mt)
#pragma unroll
      for (int nt = 0; nt < 4; ++nt)
        acc[mt][nt] = __builtin_amdgcn_mfma_f32_16x16x32_bf16(af[mt], bfr[nt], acc[mt][nt], 0, 0, 0);
    __syncthreads();
  }
  // epilogue: C/D layout col=lane&15, row=(lane>>4)*4+reg
  int crow = (lane >> 4) * 4;
  int ccol = lane & 15;
#pragma unroll
  for (int mt = 0; mt < 4; ++mt)
#pragma unroll
    for (int nt = 0; nt < 4; ++nt)
#pragma unroll
      for (int r = 0; r < 4; ++r) {
        float v = acc[mt][nt][r];
        if (GELU) v = 0.5f * v * (1.f + erff(v * 0.70710678118654752f));
        Ce[(size_t)(m0 + wm + mt * 16 + crow + r) * NN + (n0 + wn + nt * 16 + ccol)] = f2bf(v);
      }
}

// ---------------- Combine: out[t] = sum_k w_k * EO[e_k][rank_k] ----------------
__global__ void combine_kernel(const unsigned short* __restrict__ EO,
                               const int* __restrict__ top1, const int* __restrict__ top2,
                               const float* __restrict__ p0, const float* __restrict__ p1,
                               const int* __restrict__ rank0, const int* __restrict__ rank1,
                               float* __restrict__ out) {
  int t = blockIdx.x;
  int d = threadIdx.x * 4;
  float a0 = 0.f, a1 = 0.f, a2 = 0.f, a3 = 0.f;
  int r0 = rank0[t];
  if (r0 >= 0) {
    float w = p0[t];
    ushort4 v = *(const ushort4*)(EO + ((size_t)top1[t] * CAP + r0) * D_DIM + d);
    a0 += w * bf2f(v.x); a1 += w * bf2f(v.y); a2 += w * bf2f(v.z); a3 += w * bf2f(v.w);
  }
  int r1 = rank1[t];
  if (r1 >= 0) {
    float w = p1[t];
    ushort4 v = *(const ushort4*)(EO + ((size_t)top2[t] * CAP + r1) * D_DIM + d);
    a0 += w * bf2f(v.x); a1 += w * bf2f(v.y); a2 += w * bf2f(v.z); a3 += w * bf2f(v.w);
  }
  float4 o; o.x = a0; o.y = a1; o.z = a2; o.w = a3;
  *(float4*)(out + (size_t)t * D_DIM + d) = o;
}

// ---------------- Losses ----------------
__global__ void finalize_kernel(const float* __restrict__ probsum, const float* __restrict__ zsum,
                                const int* __restrict__ cntk, float* __restrict__ out) {
  if (threadIdx.x == 0) {
    float lb = 0.f;
    for (int e = 0; e < E_EXP; ++e)
      lb += (probsum[e] / (float)T_TOK) * ((float)cntk[e] / (float)(T_TOK * KSEL));
    out[(size_t)T_TOK * D_DIM] = lb * (float)E_EXP;
    out[(size_t)T_TOK * D_DIM + 1] = zsum[0] / (float)T_TOK;
  }
}

extern "C" void kernel_launch(void* const* d_in, const int* in_sizes, int n_in,
                              void* d_out, int out_size, void* d_ws, size_t ws_size,
                              hipStream_t stream) {
  const float* x = (const float*)d_in[0];
  const float* w_gate = (const float*)d_in[1];
  const float* w_fc = (const float*)d_in[2];
  const float* w_proj = (const float*)d_in[3];
  float* out = (float*)d_out;
  char* ws = (char*)d_ws;

  float* probsum = (float*)(ws + 0);
  float* zsum    = (float*)(ws + 32);
  int*   cntk    = (int*)(ws + 64);
  int*   top1    = (int*)(ws + 4096);
  int*   top2    = (int*)(ws + 20480);
  float* p0      = (float*)(ws + 36864);
  float* p1      = (float*)(ws + 53248);
  int*   rank0   = (int*)(ws + 69632);
  int*   rank1   = (int*)(ws + 86016);
  int*   slot    = (int*)(ws + 102400);
  unsigned short* batch = (unsigned short*)(ws + 262144);                        // 20.97 MB
  unsigned short* H     = (unsigned short*)(ws + 262144 + 20971520);             // 83.9 MB
  unsigned short* EO    = (unsigned short*)(ws + 262144 + 20971520 + 83886080);  // 20.97 MB
  unsigned short* W     = (unsigned short*)(ws + 262144 + 20971520 + 83886080 + 20971520); // 67.1 MB

  hipMemsetAsync(ws, 0, 4096, stream);
  hipMemsetAsync(slot, 0xFF, E_EXP * CAP * sizeof(int), stream);

  router_kernel<<<T_TOK / 4, 256, 0, stream>>>(x, w_gate, top1, top2, p0, p1, probsum, zsum);
  scan_kernel<<<1, 256, 0, stream>>>(top1, top2, rank0, rank1, slot, cntk);
  dispatch_kernel<<<E_EXP * CAP, 256, 0, stream>>>(x, slot, batch);

  // wT_fc[e][hid][d] <- w_fc[e][d][hid]
  transpose_convert<<<dim3(HID_DIM / 64, D_DIM / 64, E_EXP), 256, 0, stream>>>(w_fc, W, D_DIM, HID_DIM);
  // GEMM1: [CAP x 1024] x [4096 x 1024]^T, n-groups of 4 tiles (512 cols, 1 MB B-slice)
  gemm_alds<D_DIM, HID_DIM, 4, true><<<8 * (HID_DIM / 128 / 4) * (CAP / 128) * 4, 256, 0, stream>>>(batch, W, H, cntk);

  // wT_proj[e][d][hid] <- w_proj[e][hid][d]  (reuses W, stream-ordered)
  transpose_convert<<<dim3(D_DIM / 64, HID_DIM / 64, E_EXP), 256, 0, stream>>>(w_proj, W, HID_DIM, D_DIM);
  // GEMM2: [CAP x 4096] x [1024 x 4096]^T, n-groups of 2 tiles (2.1 MB B-slice)
  gemm_alds<HID_DIM, D_DIM, 2, false><<<8 * (D_DIM / 128 / 2) * (CAP / 128) * 2, 256, 0, stream>>>(H, W, EO, cntk);

  combine_kernel<<<T_TOK, 256, 0, stream>>>(EO, top1, top2, p0, p1, rank0, rank1, out);
  finalize_kernel<<<1, 64, 0, stream>>>(probsum, zsum, cntk, out);
}